// Round 4
// baseline (3696.811 us; speedup 1.0000x reference)
//
#include <hip/hip_runtime.h>
#include <hip/hip_bf16.h>

#define GRID_W 64
#define NPTS   4096
#define BATCH  8
#define DD     32
#define DIN    80
#define HID    128
#define SH_STRIDE 136              // ushort stride (17*16B) -> conflict-free b128
#define NBLK   256
// ws layout: [0..255] barrier | fragment-packed bf16 weights
#define OFF_F1Q 256
#define OFF_F2Q (OFF_F1Q + 24*64*16)   // 24 GEMM1 frags * 64 lanes * 16B
#define OFF_F1P (OFF_F2Q + 8*64*16)    //  8 GEMM2 frags
#define OFF_F2P (OFF_F1P + 24*64*16)

typedef __attribute__((ext_vector_type(8))) short short8;
typedef __attribute__((ext_vector_type(4))) float f32x4;

__device__ __forceinline__ ushort f2bf(float v) {
    __hip_bfloat16 h = __float2bfloat16(v);
    return __builtin_bit_cast(ushort, h);
}
__device__ __forceinline__ uint packbf(float a, float b) {
    return (uint)f2bf(a) | ((uint)f2bf(b) << 16);
}
__device__ __forceinline__ short8 pack8(float4 a, float4 b) {
    union { uint u[4]; short8 s; } t;
    t.u[0] = packbf(a.x, a.y); t.u[1] = packbf(a.z, a.w);
    t.u[2] = packbf(b.x, b.y); t.u[3] = packbf(b.z, b.w);
    return t.s;
}

// Pack W1/W2 (both sets) into MFMA B-fragment order in ws:
// f1[(ks*8+nt)*64 + lane][j] = bf16(W1[ks*32 + (lane>>4)*8 + j][nt*16 + (lane&15)])
__global__ void pack_weights(const float* __restrict__ W1q, const float* __restrict__ W2q,
                             const float* __restrict__ W1p, const float* __restrict__ W2p,
                             char* __restrict__ ws)
{
    const int s = blockIdx.x;
    const float* W1 = s ? W1p : W1q;
    const float* W2 = s ? W2p : W2q;
    ushort* f1 = (ushort*)(ws + (s ? OFF_F1P : OFF_F1Q));
    ushort* f2 = (ushort*)(ws + (s ? OFF_F2P : OFF_F2Q));
    for (int idx = threadIdx.x; idx < 24 * 512; idx += 256) {
        int f = idx >> 9, rem = idx & 511, lane = rem >> 3, j = rem & 7;
        int ks = f >> 3, nt = f & 7;
        int k = ks * 32 + (lane >> 4) * 8 + j, n = nt * 16 + (lane & 15);
        f1[idx] = f2bf(k < DIN ? W1[k * HID + n] : 0.0f);
    }
    for (int idx = threadIdx.x; idx < 8 * 512; idx += 256) {
        int f = idx >> 9, rem = idx & 511, lane = rem >> 3, j = rem & 7;
        int ks = f >> 1, nt = f & 1;
        int k = ks * 32 + (lane >> 4) * 8 + j, n = nt * 16 + (lane & 15);
        f2[idx] = f2bf(W2[k * DD + n]);
    }
}

// Grid-wide generation barrier; all-thread fences (cg-style), 256 arrivals.
__device__ __forceinline__ void grid_sync(uint* bar) {
    __threadfence();
    __syncthreads();
    if (threadIdx.x == 0) {
        uint g = __hip_atomic_load(&bar[1], __ATOMIC_RELAXED, __HIP_MEMORY_SCOPE_AGENT);
        uint a = __hip_atomic_fetch_add(&bar[0], 1u, __ATOMIC_ACQ_REL, __HIP_MEMORY_SCOPE_AGENT);
        if (a == NBLK - 1) {
            __hip_atomic_store(&bar[0], 0u, __ATOMIC_RELAXED, __HIP_MEMORY_SCOPE_AGENT);
            __hip_atomic_store(&bar[1], g + 1u, __ATOMIC_RELEASE, __HIP_MEMORY_SCOPE_AGENT);
        } else {
            while (__hip_atomic_load(&bar[1], __ATOMIC_ACQUIRE, __HIP_MEMORY_SCOPE_AGENT) == g)
                __builtin_amdgcn_s_sleep(2);
        }
    }
    __syncthreads();
    __threadfence();
}

// One half-step for this block's two 64-point row tiles. No intra-step
// __syncthreads: every LDS region touched is wave-local.
__device__ __forceinline__ void do_step(
    float* __restrict__ state, const float* __restrict__ tfinal,
    const char* __restrict__ ws,
    const float* __restrict__ B1, const float* __restrict__ B2,
    ushort* __restrict__ sH /*[2][64*SH_STRIDE]*/, float* __restrict__ sO /*[8][512]*/,
    int blk, int tid, int phase, float tcur, float dtmax)
{
    const int w = tid >> 6, lane = tid & 63;
    const int t = w >> 2, wv = w & 3;
    const int l16 = lane & 15, quad = lane >> 4, q8 = quad * 8;
    const int R = blk * 2 + t;             // row-tile 0..511
    const int b = R >> 6, r = R & 63;      // b is block-uniform (R=2*blk+t)
    const int c = wv * 16 + l16;           // point column = GEMM row

    const float tf = tfinal[b];
    const float dt = fminf(fmaxf(tf - tcur, 0.0f), dtmax);
    if (dt <= 0.0f) return;                // exact: z + 0*F == z

    const int srcoff = phase ? 0 : DD;     // phase0: q += dt*F(p); phase1: p += dt*F(q)
    const int dstoff = phase ? DD : 0;
    float* bb = state + (size_t)b * NPTS * DIN;
    const float* selfp = bb + (r * GRID_W + c) * DIN;

    // ---- gather A fragments (registers) ----
    const int rm = (r + 63) & 63, rp = (r + 1) & 63;
    const int cm = (c + 63) & 63, cp = (c + 1) & 63;
    short8 af0, af1, af2;
    {
        const float* ps = selfp + srcoff + q8;
        af0 = pack8(*(const float4*)ps, *(const float4*)(ps + 4));
    }
    {
        const float* p0 = bb + (rm * GRID_W + c) * DIN + srcoff + q8;
        const float* p1 = bb + (rp * GRID_W + c) * DIN + srcoff + q8;
        const float* p2 = bb + (r * GRID_W + cm) * DIN + srcoff + q8;
        const float* p3 = bb + (r * GRID_W + cp) * DIN + srcoff + q8;
        float4 a0 = *(const float4*)p0, a1 = *(const float4*)(p0 + 4);
        float4 b0 = *(const float4*)p1, b1v = *(const float4*)(p1 + 4);
        float4 c0 = *(const float4*)p2, c1 = *(const float4*)(p2 + 4);
        float4 d0 = *(const float4*)p3, d1 = *(const float4*)(p3 + 4);
        float4 m0, m1;
        m0.x = 0.25f * (a0.x + b0.x + c0.x + d0.x);
        m0.y = 0.25f * (a0.y + b0.y + c0.y + d0.y);
        m0.z = 0.25f * (a0.z + b0.z + c0.z + d0.z);
        m0.w = 0.25f * (a0.w + b0.w + c0.w + d0.w);
        m1.x = 0.25f * (a1.x + b1v.x + c1.x + d1.x);
        m1.y = 0.25f * (a1.y + b1v.y + c1.y + d1.y);
        m1.z = 0.25f * (a1.z + b1v.z + c1.z + d1.z);
        m1.w = 0.25f * (a1.w + b1v.w + c1.w + d1.w);
        af1 = pack8(m0, m1);
    }
    if (quad < 2) {
        const float* px = selfp + 2 * DD + q8;
        af2 = pack8(*(const float4*)px, *(const float4*)(px + 4));
    } else {
        af2 = (short8)(short)0;
    }

    // ---- GEMM1: H = tanh(A @ W1 + b1); B-fragments from ws (coalesced, L2) ----
    const short8* F1 = (const short8*)(ws + (phase ? OFF_F1P : OFF_F1Q));
    const short8* F2 = (const short8*)(ws + (phase ? OFF_F2P : OFF_F2Q));

    f32x4 acc1[8];
    #pragma unroll
    for (int nt = 0; nt < 8; ++nt) acc1[nt] = (f32x4){0.f, 0.f, 0.f, 0.f};
    #pragma unroll
    for (int nt = 0; nt < 8; ++nt)
        acc1[nt] = __builtin_amdgcn_mfma_f32_16x16x32_bf16(af0, F1[(0 * 8 + nt) * 64 + lane], acc1[nt], 0, 0, 0);
    #pragma unroll
    for (int nt = 0; nt < 8; ++nt)
        acc1[nt] = __builtin_amdgcn_mfma_f32_16x16x32_bf16(af1, F1[(1 * 8 + nt) * 64 + lane], acc1[nt], 0, 0, 0);
    #pragma unroll
    for (int nt = 0; nt < 8; ++nt)
        acc1[nt] = __builtin_amdgcn_mfma_f32_16x16x32_bf16(af2, F1[(2 * 8 + nt) * 64 + lane], acc1[nt], 0, 0, 0);

    // tanh -> sH tile (C-layout: col=lane&15, row=quad*4+reg). Wave-local rows.
    ushort* sHt = sH + t * 64 * SH_STRIDE;
    #pragma unroll
    for (int nt = 0; nt < 8; ++nt) {
        const int col = nt * 16 + l16;
        const float bias = B1[col];
        #pragma unroll
        for (int rg = 0; rg < 4; ++rg) {
            const int rowm = wv * 16 + quad * 4 + rg;
            float s = acc1[nt][rg] + bias;
            float e = __expf(2.0f * s);
            float hh = 1.0f - __fdividef(2.0f, e + 1.0f);
            sHt[rowm * SH_STRIDE + col] = f2bf(hh);
        }
    }

    // ---- GEMM2: O = H @ W2 + b2 ----
    f32x4 acc2[2];
    acc2[0] = (f32x4){0.f, 0.f, 0.f, 0.f};
    acc2[1] = (f32x4){0.f, 0.f, 0.f, 0.f};
    #pragma unroll
    for (int ks = 0; ks < 4; ++ks) {
        short8 af = *(const short8*)&sHt[(wv * 16 + l16) * SH_STRIDE + ks * 32 + q8];
        #pragma unroll
        for (int nt = 0; nt < 2; ++nt)
            acc2[nt] = __builtin_amdgcn_mfma_f32_16x16x32_bf16(af, F2[(ks * 2 + nt) * 64 + lane], acc2[nt], 0, 0, 0);
    }

    // ---- O -> wave-private sO, then coalesced float4 RMW epilogue ----
    float* sOw = sO + w * 512;             // 16 rows x 32 f32
    #pragma unroll
    for (int nt = 0; nt < 2; ++nt) {
        const int col = nt * 16 + l16;
        const float b2v = B2[col];
        #pragma unroll
        for (int rg = 0; rg < 4; ++rg)
            sOw[(quad * 4 + rg) * DD + col] = acc2[nt][rg] + b2v;
    }
    #pragma unroll
    for (int it = 0; it < 2; ++it) {
        const int slot = lane + it * 64;   // 128 float4 slots = 16 rows x 8
        const int lr = slot >> 3, seg = (slot & 7) * 4;
        float* pd = bb + (r * GRID_W + wv * 16 + lr) * DIN + dstoff + seg;
        const float* po = &sOw[lr * DD + seg];
        float4 o = *(const float4*)pd;
        o.x += dt * po[0]; o.y += dt * po[1];
        o.z += dt * po[2]; o.w += dt * po[3];
        *(float4*)pd = o;
    }
}

__global__ __launch_bounds__(512, 2) void sympl_coop(
    float* __restrict__ state, const float* __restrict__ tfinal,
    char* __restrict__ ws,
    const float* __restrict__ b1q, const float* __restrict__ b2q,
    const float* __restrict__ b1p, const float* __restrict__ b2p)
{
    __shared__ __align__(16) ushort sH[2 * 64 * SH_STRIDE];
    __shared__ __align__(16) float  sO[8 * 512];
    uint* bar = (uint*)ws;
    const int blk = blockIdx.x, tid = threadIdx.x;

    float tq = 0.0f, tp = 0.0f;
    #pragma unroll 1
    for (int h = 0; h < 36; ++h) {
        const int phase = h & 1;
        const float dtmax = phase ? 0.25f : ((h == 0) ? 0.125f : 0.25f);
        const float tcur  = phase ? tp : tq;
        do_step(state, tfinal, ws,
                phase ? b1p : b1q, phase ? b2p : b2q,
                sH, sO, blk, tid, phase, tcur, dtmax);
        if (phase) tp += dtmax; else tq += dtmax;
        if (h < 35) grid_sync(bar);
    }
}

__global__ __launch_bounds__(512, 2) void sympl_step(
    float* __restrict__ state, const float* __restrict__ tfinal,
    const char* __restrict__ ws,
    const float* __restrict__ B1, const float* __restrict__ B2,
    int phase, float tcur, float dtmax)
{
    __shared__ __align__(16) ushort sH[2 * 64 * SH_STRIDE];
    __shared__ __align__(16) float  sO[8 * 512];
    do_step(state, tfinal, ws, B1, B2, sH, sO,
            blockIdx.x, threadIdx.x, phase, tcur, dtmax);
}

extern "C" void kernel_launch(void* const* d_in, const int* in_sizes, int n_in,
                              void* d_out, int out_size, void* d_ws, size_t ws_size,
                              hipStream_t stream)
{
    const float* x   = (const float*)d_in[0];
    const float* tf  = (const float*)d_in[1];
    const float* W1q = (const float*)d_in[2];
    const float* b1q = (const float*)d_in[3];
    const float* W2q = (const float*)d_in[4];
    const float* b2q = (const float*)d_in[5];
    const float* W1p = (const float*)d_in[6];
    const float* b1p = (const float*)d_in[7];
    const float* W2p = (const float*)d_in[8];
    const float* b2p = (const float*)d_in[9];
    float* out = (float*)d_out;
    char* ws = (char*)d_ws;

    // state lives in d_out: [b][i][q(32) p(32) xi(16)]
    hipMemcpyAsync(out, x, (size_t)BATCH * NPTS * DIN * sizeof(float),
                   hipMemcpyDeviceToDevice, stream);
    hipMemsetAsync(ws, 0, 16, stream);                 // barrier words
    pack_weights<<<dim3(2), dim3(256), 0, stream>>>(W1q, W2q, W1p, W2p, ws);

    void* args[] = { (void*)&out, (void*)&tf, (void*)&ws,
                     (void*)&b1q, (void*)&b2q, (void*)&b1p, (void*)&b2p };
    hipError_t e = hipLaunchCooperativeKernel((const void*)sympl_coop,
                                              dim3(NBLK), dim3(512), args, 0, stream);
    if (e != hipSuccess) {
        // Fallback: same math as 36 regular launches (no grid barrier needed).
        float tq = 0.0f, tp = 0.0f;
        for (int h = 0; h < 36; ++h) {
            const int phase = h & 1;
            const float dtmax = phase ? 0.25f : ((h == 0) ? 0.125f : 0.25f);
            const float tcur  = phase ? tp : tq;
            sympl_step<<<dim3(NBLK), dim3(512), 0, stream>>>(
                out, tf, ws, phase ? b1p : b1q, phase ? b2p : b2q,
                phase, tcur, dtmax);
            if (phase) tp += dtmax; else tq += dtmax;
        }
    }
}

// Round 5
// 620.928 us; speedup vs baseline: 5.9537x; 5.9537x over previous
//
#include <hip/hip_runtime.h>
#include <hip/hip_bf16.h>

#define GRID_W 64
#define NPTS   4096
#define BATCH  8
#define DD     32
#define DIN    80
#define HID    128
#define SH_STRIDE 136              // ushort stride (17*16B) -> conflict-free b128
#define NBLK   256
#define NSTEP  34                  // steps 34,35 are dead for any tf <= 4.0
// ws layout: [0..255] barrier | fragment-packed bf16 weights
#define OFF_F1Q 256
#define OFF_F2Q (OFF_F1Q + 24*64*16)   // 24 GEMM1 frags * 64 lanes * 16B
#define OFF_F1P (OFF_F2Q + 8*64*16)    //  8 GEMM2 frags
#define OFF_F2P (OFF_F1P + 24*64*16)

typedef __attribute__((ext_vector_type(8))) short short8;
typedef __attribute__((ext_vector_type(4))) float f32x4;

__device__ __forceinline__ ushort f2bf(float v) {
    __hip_bfloat16 h = __float2bfloat16(v);
    return __builtin_bit_cast(ushort, h);
}
__device__ __forceinline__ uint packbf(float a, float b) {
    return (uint)f2bf(a) | ((uint)f2bf(b) << 16);
}
__device__ __forceinline__ short8 pack8(float4 a, float4 b) {
    union { uint u[4]; short8 s; } t;
    t.u[0] = packbf(a.x, a.y); t.u[1] = packbf(a.z, a.w);
    t.u[2] = packbf(b.x, b.y); t.u[3] = packbf(b.z, b.w);
    return t.s;
}

// Pack W1/W2 (both sets) into MFMA B-fragment order in ws:
// f1[(ks*8+nt)*64 + lane][j] = bf16(W1[ks*32 + (lane>>4)*8 + j][nt*16 + (lane&15)])
__global__ void pack_weights(const float* __restrict__ W1q, const float* __restrict__ W2q,
                             const float* __restrict__ W1p, const float* __restrict__ W2p,
                             char* __restrict__ ws)
{
    const int s = blockIdx.x;
    const float* W1 = s ? W1p : W1q;
    const float* W2 = s ? W2p : W2q;
    ushort* f1 = (ushort*)(ws + (s ? OFF_F1P : OFF_F1Q));
    ushort* f2 = (ushort*)(ws + (s ? OFF_F2P : OFF_F2Q));
    for (int idx = threadIdx.x; idx < 24 * 512; idx += 256) {
        int f = idx >> 9, rem = idx & 511, lane = rem >> 3, j = rem & 7;
        int ks = f >> 3, nt = f & 7;
        int k = ks * 32 + (lane >> 4) * 8 + j, n = nt * 16 + (lane & 15);
        f1[idx] = f2bf(k < DIN ? W1[k * HID + n] : 0.0f);
    }
    for (int idx = threadIdx.x; idx < 8 * 512; idx += 256) {
        int f = idx >> 9, rem = idx & 511, lane = rem >> 3, j = rem & 7;
        int ks = f >> 1, nt = f & 1;
        int k = ks * 32 + (lane >> 4) * 8 + j, n = nt * 16 + (lane & 15);
        f2[idx] = f2bf(W2[k * DD + n]);
    }
}

// Grid-wide generation barrier. Fences ONLY in thread 0 (one buffer_wbl2 /
// buffer_inv per block, not per thread): __syncthreads drains vmcnt so all
// block writes are in (write-through) L2; the release half of the arrival
// fetch_add publishes them; a single acquire fence after the generation bump
// invalidates this CU's stale cache state for everyone in the block.
__device__ __forceinline__ void grid_sync(uint* bar) {
    __syncthreads();
    if (threadIdx.x == 0) {
        uint g = __hip_atomic_load(&bar[1], __ATOMIC_RELAXED, __HIP_MEMORY_SCOPE_AGENT);
        uint a = __hip_atomic_fetch_add(&bar[0], 1u, __ATOMIC_ACQ_REL, __HIP_MEMORY_SCOPE_AGENT);
        if (a == NBLK - 1) {
            __hip_atomic_store(&bar[0], 0u, __ATOMIC_RELAXED, __HIP_MEMORY_SCOPE_AGENT);
            __hip_atomic_store(&bar[1], g + 1u, __ATOMIC_RELEASE, __HIP_MEMORY_SCOPE_AGENT);
            // leader arrived last: its ACQ_REL fetch_add already acquired
        } else {
            while (__hip_atomic_load(&bar[1], __ATOMIC_RELAXED, __HIP_MEMORY_SCOPE_AGENT) == g)
                __builtin_amdgcn_s_sleep(1);
            __builtin_amdgcn_fence(__ATOMIC_ACQUIRE, "agent");
        }
    }
    __syncthreads();
}

// One half-step for this block's two 64-point row tiles. No intra-step
// __syncthreads: every LDS region touched is wave-local.
__device__ __forceinline__ void do_step(
    float* __restrict__ state, const float* __restrict__ tfinal,
    const char* __restrict__ ws,
    const float* __restrict__ B1, const float* __restrict__ B2,
    ushort* __restrict__ sH /*[2][64*SH_STRIDE]*/, float* __restrict__ sO /*[8][512]*/,
    int blk, int tid, int phase, float tcur, float dtmax)
{
    const int w = tid >> 6, lane = tid & 63;
    const int t = w >> 2, wv = w & 3;
    const int l16 = lane & 15, quad = lane >> 4, q8 = quad * 8;
    const int R = blk * 2 + t;             // row-tile 0..511
    const int b = R >> 6, r = R & 63;
    const int c = wv * 16 + l16;           // point column = GEMM row

    const float tf = tfinal[b];
    const float dt = fminf(fmaxf(tf - tcur, 0.0f), dtmax);
    if (dt <= 0.0f) return;                // exact: z + 0*F == z

    const int srcoff = phase ? 0 : DD;     // phase0: q += dt*F(p); phase1: p += dt*F(q)
    const int dstoff = phase ? DD : 0;
    float* bb = state + (size_t)b * NPTS * DIN;
    const float* selfp = bb + (r * GRID_W + c) * DIN;

    // ---- gather A fragments (registers) ----
    const int rm = (r + 63) & 63, rp = (r + 1) & 63;
    const int cm = (c + 63) & 63, cp = (c + 1) & 63;
    short8 af0, af1, af2;
    {
        const float* ps = selfp + srcoff + q8;
        af0 = pack8(*(const float4*)ps, *(const float4*)(ps + 4));
    }
    {
        const float* p0 = bb + (rm * GRID_W + c) * DIN + srcoff + q8;
        const float* p1 = bb + (rp * GRID_W + c) * DIN + srcoff + q8;
        const float* p2 = bb + (r * GRID_W + cm) * DIN + srcoff + q8;
        const float* p3 = bb + (r * GRID_W + cp) * DIN + srcoff + q8;
        float4 a0 = *(const float4*)p0, a1 = *(const float4*)(p0 + 4);
        float4 b0 = *(const float4*)p1, b1v = *(const float4*)(p1 + 4);
        float4 c0 = *(const float4*)p2, c1 = *(const float4*)(p2 + 4);
        float4 d0 = *(const float4*)p3, d1 = *(const float4*)(p3 + 4);
        float4 m0, m1;
        m0.x = 0.25f * (a0.x + b0.x + c0.x + d0.x);
        m0.y = 0.25f * (a0.y + b0.y + c0.y + d0.y);
        m0.z = 0.25f * (a0.z + b0.z + c0.z + d0.z);
        m0.w = 0.25f * (a0.w + b0.w + c0.w + d0.w);
        m1.x = 0.25f * (a1.x + b1v.x + c1.x + d1.x);
        m1.y = 0.25f * (a1.y + b1v.y + c1.y + d1.y);
        m1.z = 0.25f * (a1.z + b1v.z + c1.z + d1.z);
        m1.w = 0.25f * (a1.w + b1v.w + c1.w + d1.w);
        af1 = pack8(m0, m1);
    }
    if (quad < 2) {
        const float* px = selfp + 2 * DD + q8;
        af2 = pack8(*(const float4*)px, *(const float4*)(px + 4));
    } else {
        af2 = (short8)(short)0;
    }

    // ---- GEMM1: H = tanh(A @ W1 + b1); B-fragments from ws (coalesced, L2) ----
    const short8* F1 = (const short8*)(ws + (phase ? OFF_F1P : OFF_F1Q));
    const short8* F2 = (const short8*)(ws + (phase ? OFF_F2P : OFF_F2Q));

    f32x4 acc1[8];
    #pragma unroll
    for (int nt = 0; nt < 8; ++nt) acc1[nt] = (f32x4){0.f, 0.f, 0.f, 0.f};
    #pragma unroll
    for (int nt = 0; nt < 8; ++nt)
        acc1[nt] = __builtin_amdgcn_mfma_f32_16x16x32_bf16(af0, F1[(0 * 8 + nt) * 64 + lane], acc1[nt], 0, 0, 0);
    #pragma unroll
    for (int nt = 0; nt < 8; ++nt)
        acc1[nt] = __builtin_amdgcn_mfma_f32_16x16x32_bf16(af1, F1[(1 * 8 + nt) * 64 + lane], acc1[nt], 0, 0, 0);
    #pragma unroll
    for (int nt = 0; nt < 8; ++nt)
        acc1[nt] = __builtin_amdgcn_mfma_f32_16x16x32_bf16(af2, F1[(2 * 8 + nt) * 64 + lane], acc1[nt], 0, 0, 0);

    // tanh -> sH tile (C-layout: col=lane&15, row=quad*4+reg). Wave-local rows.
    ushort* sHt = sH + t * 64 * SH_STRIDE;
    #pragma unroll
    for (int nt = 0; nt < 8; ++nt) {
        const int col = nt * 16 + l16;
        const float bias = B1[col];
        #pragma unroll
        for (int rg = 0; rg < 4; ++rg) {
            const int rowm = wv * 16 + quad * 4 + rg;
            float s = acc1[nt][rg] + bias;
            float e = __expf(2.0f * s);
            float hh = 1.0f - __fdividef(2.0f, e + 1.0f);
            sHt[rowm * SH_STRIDE + col] = f2bf(hh);
        }
    }

    // ---- GEMM2: O = H @ W2 + b2 ----
    f32x4 acc2[2];
    acc2[0] = (f32x4){0.f, 0.f, 0.f, 0.f};
    acc2[1] = (f32x4){0.f, 0.f, 0.f, 0.f};
    #pragma unroll
    for (int ks = 0; ks < 4; ++ks) {
        short8 af = *(const short8*)&sHt[(wv * 16 + l16) * SH_STRIDE + ks * 32 + q8];
        #pragma unroll
        for (int nt = 0; nt < 2; ++nt)
            acc2[nt] = __builtin_amdgcn_mfma_f32_16x16x32_bf16(af, F2[(ks * 2 + nt) * 64 + lane], acc2[nt], 0, 0, 0);
    }

    // ---- O -> wave-private sO, then coalesced float4 RMW epilogue ----
    float* sOw = sO + w * 512;             // 16 rows x 32 f32
    #pragma unroll
    for (int nt = 0; nt < 2; ++nt) {
        const int col = nt * 16 + l16;
        const float b2v = B2[col];
        #pragma unroll
        for (int rg = 0; rg < 4; ++rg)
            sOw[(quad * 4 + rg) * DD + col] = acc2[nt][rg] + b2v;
    }
    #pragma unroll
    for (int it = 0; it < 2; ++it) {
        const int slot = lane + it * 64;   // 128 float4 slots = 16 rows x 8
        const int lr = slot >> 3, seg = (slot & 7) * 4;
        float* pd = bb + (r * GRID_W + wv * 16 + lr) * DIN + dstoff + seg;
        const float* po = &sOw[lr * DD + seg];
        float4 o = *(const float4*)pd;
        o.x += dt * po[0]; o.y += dt * po[1];
        o.z += dt * po[2]; o.w += dt * po[3];
        *(float4*)pd = o;
    }
}

__global__ __launch_bounds__(512, 2) void sympl_coop(
    float* __restrict__ state, const float* __restrict__ tfinal,
    char* __restrict__ ws,
    const float* __restrict__ b1q, const float* __restrict__ b2q,
    const float* __restrict__ b1p, const float* __restrict__ b2p)
{
    __shared__ __align__(16) ushort sH[2 * 64 * SH_STRIDE];
    __shared__ __align__(16) float  sO[8 * 512];
    uint* bar = (uint*)ws;
    const int blk = blockIdx.x, tid = threadIdx.x;

    // grid-uniform early-exit bound: no step with tcur >= max_b tf can do work
    float tfmax = 0.0f;
    #pragma unroll
    for (int i = 0; i < BATCH; ++i) tfmax = fmaxf(tfmax, tfinal[i]);

    float tq = 0.0f, tp = 0.0f;
    #pragma unroll 1
    for (int h = 0; h < NSTEP; ++h) {
        const int phase = h & 1;
        const float dtmax = phase ? 0.25f : ((h == 0) ? 0.125f : 0.25f);
        const float tcur  = phase ? tp : tq;
        if (tcur >= tfmax) break;          // monotone in h; identical on all blocks
        if (h > 0) grid_sync(bar);
        do_step(state, tfinal, ws,
                phase ? b1p : b1q, phase ? b2p : b2q,
                sH, sO, blk, tid, phase, tcur, dtmax);
        if (phase) tp += dtmax; else tq += dtmax;
    }
}

__global__ __launch_bounds__(512, 2) void sympl_step(
    float* __restrict__ state, const float* __restrict__ tfinal,
    const char* __restrict__ ws,
    const float* __restrict__ B1, const float* __restrict__ B2,
    int phase, float tcur, float dtmax)
{
    __shared__ __align__(16) ushort sH[2 * 64 * SH_STRIDE];
    __shared__ __align__(16) float  sO[8 * 512];
    do_step(state, tfinal, ws, B1, B2, sH, sO,
            blockIdx.x, threadIdx.x, phase, tcur, dtmax);
}

extern "C" void kernel_launch(void* const* d_in, const int* in_sizes, int n_in,
                              void* d_out, int out_size, void* d_ws, size_t ws_size,
                              hipStream_t stream)
{
    const float* x   = (const float*)d_in[0];
    const float* tf  = (const float*)d_in[1];
    const float* W1q = (const float*)d_in[2];
    const float* b1q = (const float*)d_in[3];
    const float* W2q = (const float*)d_in[4];
    const float* b2q = (const float*)d_in[5];
    const float* W1p = (const float*)d_in[6];
    const float* b1p = (const float*)d_in[7];
    const float* W2p = (const float*)d_in[8];
    const float* b2p = (const float*)d_in[9];
    float* out = (float*)d_out;
    char* ws = (char*)d_ws;

    // state lives in d_out: [b][i][q(32) p(32) xi(16)]
    hipMemcpyAsync(out, x, (size_t)BATCH * NPTS * DIN * sizeof(float),
                   hipMemcpyDeviceToDevice, stream);
    hipMemsetAsync(ws, 0, 16, stream);                 // barrier words
    pack_weights<<<dim3(2), dim3(256), 0, stream>>>(W1q, W2q, W1p, W2p, ws);

    void* args[] = { (void*)&out, (void*)&tf, (void*)&ws,
                     (void*)&b1q, (void*)&b2q, (void*)&b1p, (void*)&b2p };
    hipError_t e = hipLaunchCooperativeKernel((const void*)sympl_coop,
                                              dim3(NBLK), dim3(512), args, 0, stream);
    if (e != hipSuccess) {
        // Fallback: same math as 34 regular launches (no grid barrier needed).
        float tq = 0.0f, tp = 0.0f;
        for (int h = 0; h < NSTEP; ++h) {
            const int phase = h & 1;
            const float dtmax = phase ? 0.25f : ((h == 0) ? 0.125f : 0.25f);
            const float tcur  = phase ? tp : tq;
            sympl_step<<<dim3(NBLK), dim3(512), 0, stream>>>(
                out, tf, ws, phase ? b1p : b1q, phase ? b2p : b2q,
                phase, tcur, dtmax);
            if (phase) tp += dtmax; else tq += dtmax;
        }
    }
}

// Round 6
// 508.767 us; speedup vs baseline: 7.2662x; 1.2205x over previous
//
#include <hip/hip_runtime.h>
#include <hip/hip_bf16.h>

#define GRID_W 64
#define NPTS   4096
#define BATCH  8
#define DD     32
#define DIN    80
#define HID    128
#define SH_STRIDE 136              // ushort stride (17*16B) -> conflict-free b128
#define NBLK   256
#define NSTEP  34                  // steps 34,35 are dead for any tf <= 4.0
// ws layout: [0..255] barrier | fragment-packed bf16 weights
#define OFF_F1Q 256
#define OFF_F2Q (OFF_F1Q + 24*64*16)   // 24 GEMM1 frags * 64 lanes * 16B
#define OFF_F1P (OFF_F2Q + 8*64*16)    //  8 GEMM2 frags
#define OFF_F2P (OFF_F1P + 24*64*16)

typedef __attribute__((ext_vector_type(8))) short short8;
typedef __attribute__((ext_vector_type(4))) float f32x4;
typedef unsigned long long u64;

__device__ __forceinline__ ushort f2bf(float v) {
    __hip_bfloat16 h = __float2bfloat16(v);
    return __builtin_bit_cast(ushort, h);
}
__device__ __forceinline__ uint packbf(float a, float b) {
    return (uint)f2bf(a) | ((uint)f2bf(b) << 16);
}
__device__ __forceinline__ short8 pack8(float4 a, float4 b) {
    union { uint u[4]; short8 s; } t;
    t.u[0] = packbf(a.x, a.y); t.u[1] = packbf(a.z, a.w);
    t.u[2] = packbf(b.x, b.y); t.u[3] = packbf(b.z, b.w);
    return t.s;
}

// System-scope (coherence-point) 16B load/store as 2x8B relaxed atomics.
// These emit global_load/store_dwordx2 sc0 sc1: bypass L1/L2, served by the
// die-level Infinity Cache == the cross-XCD coherence point. All q/p state
// accesses use these, so the grid barrier needs NO cache-maintenance fences
// and the read-only weights stay hot in L1/L2 across all 34 steps.
__device__ __forceinline__ float4 ld_sys4(const float* p) {
    u64 a = __hip_atomic_load((const u64*)p,       __ATOMIC_RELAXED, __HIP_MEMORY_SCOPE_SYSTEM);
    u64 b = __hip_atomic_load((const u64*)(p + 2), __ATOMIC_RELAXED, __HIP_MEMORY_SCOPE_SYSTEM);
    float4 r;
    r.x = __uint_as_float((uint)a); r.y = __uint_as_float((uint)(a >> 32));
    r.z = __uint_as_float((uint)b); r.w = __uint_as_float((uint)(b >> 32));
    return r;
}
__device__ __forceinline__ void st_sys4(float* p, float4 v) {
    u64 a = ((u64)__float_as_uint(v.y) << 32) | __float_as_uint(v.x);
    u64 b = ((u64)__float_as_uint(v.w) << 32) | __float_as_uint(v.z);
    __hip_atomic_store((u64*)p,       a, __ATOMIC_RELAXED, __HIP_MEMORY_SCOPE_SYSTEM);
    __hip_atomic_store((u64*)(p + 2), b, __ATOMIC_RELAXED, __HIP_MEMORY_SCOPE_SYSTEM);
}

// Pack W1/W2 (both sets) into MFMA B-fragment order in ws.
__global__ void pack_weights(const float* __restrict__ W1q, const float* __restrict__ W2q,
                             const float* __restrict__ W1p, const float* __restrict__ W2p,
                             char* __restrict__ ws)
{
    const int s = blockIdx.x;
    const float* W1 = s ? W1p : W1q;
    const float* W2 = s ? W2p : W2q;
    ushort* f1 = (ushort*)(ws + (s ? OFF_F1P : OFF_F1Q));
    ushort* f2 = (ushort*)(ws + (s ? OFF_F2P : OFF_F2Q));
    for (int idx = threadIdx.x; idx < 24 * 512; idx += 256) {
        int f = idx >> 9, rem = idx & 511, lane = rem >> 3, j = rem & 7;
        int ks = f >> 3, nt = f & 7;
        int k = ks * 32 + (lane >> 4) * 8 + j, n = nt * 16 + (lane & 15);
        f1[idx] = f2bf(k < DIN ? W1[k * HID + n] : 0.0f);
    }
    for (int idx = threadIdx.x; idx < 8 * 512; idx += 256) {
        int f = idx >> 9, rem = idx & 511, lane = rem >> 3, j = rem & 7;
        int ks = f >> 1, nt = f & 1;
        int k = ks * 32 + (lane >> 4) * 8 + j, n = nt * 16 + (lane & 15);
        f2[idx] = f2bf(W2[k * DD + n]);
    }
}

// Fence-free grid barrier: data coherence is handled by sc0sc1 state accesses,
// so this is a pure atomic counter. __syncthreads drains vmcnt per wave before
// thread 0 arrives, guaranteeing this block's system stores are visible.
__device__ __forceinline__ void grid_sync(uint* bar) {
    __syncthreads();
    if (threadIdx.x == 0) {
        uint g = __hip_atomic_load(&bar[1], __ATOMIC_RELAXED, __HIP_MEMORY_SCOPE_AGENT);
        uint a = __hip_atomic_fetch_add(&bar[0], 1u, __ATOMIC_RELAXED, __HIP_MEMORY_SCOPE_AGENT);
        if (a == NBLK - 1) {
            __hip_atomic_store(&bar[0], 0u, __ATOMIC_RELAXED, __HIP_MEMORY_SCOPE_AGENT);
            __hip_atomic_store(&bar[1], g + 1u, __ATOMIC_RELAXED, __HIP_MEMORY_SCOPE_AGENT);
        } else {
            while (__hip_atomic_load(&bar[1], __ATOMIC_RELAXED, __HIP_MEMORY_SCOPE_AGENT) == g)
                __builtin_amdgcn_s_sleep(1);
        }
    }
    __syncthreads();
}

// One half-step for this block's two 64-point row tiles. No intra-step
// __syncthreads: every LDS region touched is wave-local.
__device__ __forceinline__ void do_step(
    float* __restrict__ state, const float* __restrict__ tfinal,
    const char* __restrict__ ws,
    const float* __restrict__ B1, const float* __restrict__ B2,
    ushort* __restrict__ sH, float* __restrict__ sO,
    int blk, int tid, int phase, float tcur, float dtmax)
{
    const int w = tid >> 6, lane = tid & 63;
    const int t = w >> 2, wv = w & 3;
    const int l16 = lane & 15, quad = lane >> 4, q8 = quad * 8;
    const int R = blk * 2 + t;             // row-tile 0..511
    const int b = R >> 6, r = R & 63;
    const int c = wv * 16 + l16;           // point column = GEMM row

    const float tf = tfinal[b];
    const float dt = fminf(fmaxf(tf - tcur, 0.0f), dtmax);
    if (dt <= 0.0f) return;                // exact: z + 0*F == z

    const int srcoff = phase ? 0 : DD;     // phase0: q += dt*F(p); phase1: p += dt*F(q)
    const int dstoff = phase ? DD : 0;
    float* bb = state + (size_t)b * NPTS * DIN;
    const float* selfp = bb + (r * GRID_W + c) * DIN;

    // ---- gather A fragments (system-scope loads for mutable q/p) ----
    const int rm = (r + 63) & 63, rp = (r + 1) & 63;
    const int cm = (c + 63) & 63, cp = (c + 1) & 63;
    short8 af0, af1, af2;
    {
        const float* ps = selfp + srcoff + q8;
        af0 = pack8(ld_sys4(ps), ld_sys4(ps + 4));
    }
    {
        const float* p0 = bb + (rm * GRID_W + c) * DIN + srcoff + q8;
        const float* p1 = bb + (rp * GRID_W + c) * DIN + srcoff + q8;
        const float* p2 = bb + (r * GRID_W + cm) * DIN + srcoff + q8;
        const float* p3 = bb + (r * GRID_W + cp) * DIN + srcoff + q8;
        float4 a0 = ld_sys4(p0), a1 = ld_sys4(p0 + 4);
        float4 b0 = ld_sys4(p1), b1v = ld_sys4(p1 + 4);
        float4 c0 = ld_sys4(p2), c1 = ld_sys4(p2 + 4);
        float4 d0 = ld_sys4(p3), d1 = ld_sys4(p3 + 4);
        float4 m0, m1;
        m0.x = 0.25f * (a0.x + b0.x + c0.x + d0.x);
        m0.y = 0.25f * (a0.y + b0.y + c0.y + d0.y);
        m0.z = 0.25f * (a0.z + b0.z + c0.z + d0.z);
        m0.w = 0.25f * (a0.w + b0.w + c0.w + d0.w);
        m1.x = 0.25f * (a1.x + b1v.x + c1.x + d1.x);
        m1.y = 0.25f * (a1.y + b1v.y + c1.y + d1.y);
        m1.z = 0.25f * (a1.z + b1v.z + c1.z + d1.z);
        m1.w = 0.25f * (a1.w + b1v.w + c1.w + d1.w);
        af1 = pack8(m0, m1);
    }
    if (quad < 2) {                        // xi is immutable: normal cached loads
        const float* px = selfp + 2 * DD + q8;
        af2 = pack8(*(const float4*)px, *(const float4*)(px + 4));
    } else {
        af2 = (short8)(short)0;
    }

    // ---- GEMM1: H = tanh(A @ W1 + b1); B-fragments cached (hot in L1/L2) ----
    const short8* F1 = (const short8*)(ws + (phase ? OFF_F1P : OFF_F1Q));
    const short8* F2 = (const short8*)(ws + (phase ? OFF_F2P : OFF_F2Q));

    f32x4 acc1[8];
    #pragma unroll
    for (int nt = 0; nt < 8; ++nt) acc1[nt] = (f32x4){0.f, 0.f, 0.f, 0.f};
    #pragma unroll
    for (int nt = 0; nt < 8; ++nt)
        acc1[nt] = __builtin_amdgcn_mfma_f32_16x16x32_bf16(af0, F1[(0 * 8 + nt) * 64 + lane], acc1[nt], 0, 0, 0);
    #pragma unroll
    for (int nt = 0; nt < 8; ++nt)
        acc1[nt] = __builtin_amdgcn_mfma_f32_16x16x32_bf16(af1, F1[(1 * 8 + nt) * 64 + lane], acc1[nt], 0, 0, 0);
    #pragma unroll
    for (int nt = 0; nt < 8; ++nt)
        acc1[nt] = __builtin_amdgcn_mfma_f32_16x16x32_bf16(af2, F1[(2 * 8 + nt) * 64 + lane], acc1[nt], 0, 0, 0);

    // tanh -> sH tile (C-layout: col=lane&15, row=quad*4+reg). Wave-local rows.
    ushort* sHt = sH + t * 64 * SH_STRIDE;
    #pragma unroll
    for (int nt = 0; nt < 8; ++nt) {
        const int col = nt * 16 + l16;
        const float bias = B1[col];
        #pragma unroll
        for (int rg = 0; rg < 4; ++rg) {
            const int rowm = wv * 16 + quad * 4 + rg;
            float s = acc1[nt][rg] + bias;
            float e = __expf(2.0f * s);
            float hh = 1.0f - __fdividef(2.0f, e + 1.0f);
            sHt[rowm * SH_STRIDE + col] = f2bf(hh);
        }
    }

    // ---- GEMM2: O = H @ W2 + b2 ----
    f32x4 acc2[2];
    acc2[0] = (f32x4){0.f, 0.f, 0.f, 0.f};
    acc2[1] = (f32x4){0.f, 0.f, 0.f, 0.f};
    #pragma unroll
    for (int ks = 0; ks < 4; ++ks) {
        short8 af = *(const short8*)&sHt[(wv * 16 + l16) * SH_STRIDE + ks * 32 + q8];
        #pragma unroll
        for (int nt = 0; nt < 2; ++nt)
            acc2[nt] = __builtin_amdgcn_mfma_f32_16x16x32_bf16(af, F2[(ks * 2 + nt) * 64 + lane], acc2[nt], 0, 0, 0);
    }

    // ---- O -> wave-private sO, then coalesced system-scope RMW epilogue ----
    float* sOw = sO + w * 512;             // 16 rows x 32 f32
    #pragma unroll
    for (int nt = 0; nt < 2; ++nt) {
        const int col = nt * 16 + l16;
        const float b2v = B2[col];
        #pragma unroll
        for (int rg = 0; rg < 4; ++rg)
            sOw[(quad * 4 + rg) * DD + col] = acc2[nt][rg] + b2v;
    }
    #pragma unroll
    for (int it = 0; it < 2; ++it) {
        const int slot = lane + it * 64;   // 128 float4 slots = 16 rows x 8
        const int lr = slot >> 3, seg = (slot & 7) * 4;
        float* pd = bb + (r * GRID_W + wv * 16 + lr) * DIN + dstoff + seg;
        const float* po = &sOw[lr * DD + seg];
        float4 o = ld_sys4(pd);
        o.x += dt * po[0]; o.y += dt * po[1];
        o.z += dt * po[2]; o.w += dt * po[3];
        st_sys4(pd, o);
    }
}

__global__ __launch_bounds__(512, 2) void sympl_coop(
    float* __restrict__ state, const float* __restrict__ tfinal,
    char* __restrict__ ws,
    const float* __restrict__ b1q, const float* __restrict__ b2q,
    const float* __restrict__ b1p, const float* __restrict__ b2p)
{
    __shared__ __align__(16) ushort sH[2 * 64 * SH_STRIDE];
    __shared__ __align__(16) float  sO[8 * 512];
    uint* bar = (uint*)ws;
    const int blk = blockIdx.x, tid = threadIdx.x;

    // grid-uniform early-exit bound (immutable input -> identical on all blocks)
    float tfmax = 0.0f;
    #pragma unroll
    for (int i = 0; i < BATCH; ++i) tfmax = fmaxf(tfmax, tfinal[i]);

    float tq = 0.0f, tp = 0.0f;
    #pragma unroll 1
    for (int h = 0; h < NSTEP; ++h) {
        const int phase = h & 1;
        const float dtmax = phase ? 0.25f : ((h == 0) ? 0.125f : 0.25f);
        const float tcur  = phase ? tp : tq;
        if (tcur >= tfmax) break;          // monotone in h; identical on all blocks
        if (h > 0) grid_sync(bar);
        do_step(state, tfinal, ws,
                phase ? b1p : b1q, phase ? b2p : b2q,
                sH, sO, blk, tid, phase, tcur, dtmax);
        if (phase) tp += dtmax; else tq += dtmax;
    }
}

__global__ __launch_bounds__(512, 2) void sympl_step(
    float* __restrict__ state, const float* __restrict__ tfinal,
    const char* __restrict__ ws,
    const float* __restrict__ B1, const float* __restrict__ B2,
    int phase, float tcur, float dtmax)
{
    __shared__ __align__(16) ushort sH[2 * 64 * SH_STRIDE];
    __shared__ __align__(16) float  sO[8 * 512];
    do_step(state, tfinal, ws, B1, B2, sH, sO,
            blockIdx.x, threadIdx.x, phase, tcur, dtmax);
}

extern "C" void kernel_launch(void* const* d_in, const int* in_sizes, int n_in,
                              void* d_out, int out_size, void* d_ws, size_t ws_size,
                              hipStream_t stream)
{
    const float* x   = (const float*)d_in[0];
    const float* tf  = (const float*)d_in[1];
    const float* W1q = (const float*)d_in[2];
    const float* b1q = (const float*)d_in[3];
    const float* W2q = (const float*)d_in[4];
    const float* b2q = (const float*)d_in[5];
    const float* W1p = (const float*)d_in[6];
    const float* b1p = (const float*)d_in[7];
    const float* W2p = (const float*)d_in[8];
    const float* b2p = (const float*)d_in[9];
    float* out = (float*)d_out;
    char* ws = (char*)d_ws;

    // state lives in d_out: [b][i][q(32) p(32) xi(16)]
    hipMemcpyAsync(out, x, (size_t)BATCH * NPTS * DIN * sizeof(float),
                   hipMemcpyDeviceToDevice, stream);
    hipMemsetAsync(ws, 0, 16, stream);                 // barrier words
    pack_weights<<<dim3(2), dim3(256), 0, stream>>>(W1q, W2q, W1p, W2p, ws);

    void* args[] = { (void*)&out, (void*)&tf, (void*)&ws,
                     (void*)&b1q, (void*)&b2q, (void*)&b1p, (void*)&b2p };
    hipError_t e = hipLaunchCooperativeKernel((const void*)sympl_coop,
                                              dim3(NBLK), dim3(512), args, 0, stream);
    if (e != hipSuccess) {
        // Fallback: same math as 34 regular launches (kernel-boundary coherence).
        float tq = 0.0f, tp = 0.0f;
        for (int h = 0; h < NSTEP; ++h) {
            const int phase = h & 1;
            const float dtmax = phase ? 0.25f : ((h == 0) ? 0.125f : 0.25f);
            const float tcur  = phase ? tp : tq;
            sympl_step<<<dim3(NBLK), dim3(512), 0, stream>>>(
                out, tf, ws, phase ? b1p : b1q, phase ? b2p : b2q,
                phase, tcur, dtmax);
            if (phase) tp += dtmax; else tq += dtmax;
        }
    }
}

// Round 7
// 324.553 us; speedup vs baseline: 11.3905x; 1.5676x over previous
//
#include <hip/hip_runtime.h>
#include <hip/hip_bf16.h>

#define GRID_W 64
#define NPTS   4096
#define BATCH  8
#define DD     32
#define DIN    80
#define HID    128
#define SH_STRIDE 136              // ushort stride (17*16B) -> conflict-free b128
#define NBLK   512                 // one grid-row per block
#define NSTEP  34                  // steps 34,35 are dead for any tf <= 4.0
// ws layout: per-block step flags (64B line each) | fragment-packed bf16 weights
#define OFF_F1Q 32768
#define OFF_F2Q (OFF_F1Q + 24*64*16)   // 24 GEMM1 frags * 64 lanes * 16B
#define OFF_F1P (OFF_F2Q + 8*64*16)    //  8 GEMM2 frags
#define OFF_F2P (OFF_F1P + 24*64*16)

typedef __attribute__((ext_vector_type(8))) short short8;
typedef __attribute__((ext_vector_type(4))) float f32x4;
typedef unsigned long long u64;

__device__ __forceinline__ ushort f2bf(float v) {
    __hip_bfloat16 h = __float2bfloat16(v);
    return __builtin_bit_cast(ushort, h);
}
__device__ __forceinline__ uint packbf(float a, float b) {
    return (uint)f2bf(a) | ((uint)f2bf(b) << 16);
}
__device__ __forceinline__ short8 pack8(float4 a, float4 b) {
    union { uint u[4]; short8 s; } t;
    t.u[0] = packbf(a.x, a.y); t.u[1] = packbf(a.z, a.w);
    t.u[2] = packbf(b.x, b.y); t.u[3] = packbf(b.z, b.w);
    return t.s;
}

// System-scope 16B load/store as 2x8B relaxed atomics (sc0 sc1: L3-coherent,
// bypass per-XCD L2). All mutable q/p state goes through these, so cross-block
// visibility needs NO cache-maintenance fences and read-only weights stay hot
// in L1/L2 across all steps. (Validated rounds 5-6: absmax deterministic.)
__device__ __forceinline__ float4 ld_sys4(const float* p) {
    u64 a = __hip_atomic_load((const u64*)p,       __ATOMIC_RELAXED, __HIP_MEMORY_SCOPE_SYSTEM);
    u64 b = __hip_atomic_load((const u64*)(p + 2), __ATOMIC_RELAXED, __HIP_MEMORY_SCOPE_SYSTEM);
    float4 r;
    r.x = __uint_as_float((uint)a); r.y = __uint_as_float((uint)(a >> 32));
    r.z = __uint_as_float((uint)b); r.w = __uint_as_float((uint)(b >> 32));
    return r;
}
__device__ __forceinline__ void st_sys4(float* p, float4 v) {
    u64 a = ((u64)__float_as_uint(v.y) << 32) | __float_as_uint(v.x);
    u64 b = ((u64)__float_as_uint(v.w) << 32) | __float_as_uint(v.z);
    __hip_atomic_store((u64*)p,       a, __ATOMIC_RELAXED, __HIP_MEMORY_SCOPE_SYSTEM);
    __hip_atomic_store((u64*)(p + 2), b, __ATOMIC_RELAXED, __HIP_MEMORY_SCOPE_SYSTEM);
}

// Pack W1/W2 (both sets) into MFMA B-fragment order in ws.
__global__ void pack_weights(const float* __restrict__ W1q, const float* __restrict__ W2q,
                             const float* __restrict__ W1p, const float* __restrict__ W2p,
                             char* __restrict__ ws)
{
    const int s = blockIdx.x;
    const float* W1 = s ? W1p : W1q;
    const float* W2 = s ? W2p : W2q;
    ushort* f1 = (ushort*)(ws + (s ? OFF_F1P : OFF_F1Q));
    ushort* f2 = (ushort*)(ws + (s ? OFF_F2P : OFF_F2Q));
    for (int idx = threadIdx.x; idx < 24 * 512; idx += 256) {
        int f = idx >> 9, rem = idx & 511, lane = rem >> 3, j = rem & 7;
        int ks = f >> 3, nt = f & 7;
        int k = ks * 32 + (lane >> 4) * 8 + j, n = nt * 16 + (lane & 15);
        f1[idx] = f2bf(k < DIN ? W1[k * HID + n] : 0.0f);
    }
    for (int idx = threadIdx.x; idx < 8 * 512; idx += 256) {
        int f = idx >> 9, rem = idx & 511, lane = rem >> 3, j = rem & 7;
        int ks = f >> 1, nt = f & 1;
        int k = ks * 32 + (lane >> 4) * 8 + j, n = nt * 16 + (lane & 15);
        f2[idx] = f2bf(W2[k * DD + n]);
    }
}

// One half-step for this block's single 64-point grid row (4 waves).
// No intra-step __syncthreads: every LDS region touched is wave-local.
__device__ __forceinline__ void do_step(
    float* __restrict__ state, const float* __restrict__ tfinal,
    const char* __restrict__ ws,
    const float* __restrict__ B1, const float* __restrict__ B2,
    ushort* __restrict__ sH /*[64*SH_STRIDE]*/, float* __restrict__ sO /*[4*512]*/,
    int blk, int tid, int phase, float tcur, float dtmax)
{
    const int wv = tid >> 6, lane = tid & 63;
    const int l16 = lane & 15, quad = lane >> 4, q8 = quad * 8;
    const int b = blk >> 6, r = blk & 63;  // batch, grid row
    const int c = wv * 16 + l16;           // point column = GEMM row

    const float tf = tfinal[b];
    const float dt = fminf(fmaxf(tf - tcur, 0.0f), dtmax);
    if (dt <= 0.0f) return;                // exact: z + 0*F == z (block-uniform)

    const int srcoff = phase ? 0 : DD;     // phase0: q += dt*F(p); phase1: p += dt*F(q)
    const int dstoff = phase ? DD : 0;
    float* bb = state + (size_t)b * NPTS * DIN;
    const float* selfp = bb + (r * GRID_W + c) * DIN;

    // ---- gather A fragments (system-scope loads for mutable q/p) ----
    const int rm = (r + 63) & 63, rp = (r + 1) & 63;
    const int cm = (c + 63) & 63, cp = (c + 1) & 63;
    short8 af0, af1, af2;
    {
        const float* ps = selfp + srcoff + q8;
        af0 = pack8(ld_sys4(ps), ld_sys4(ps + 4));
    }
    {
        const float* p0 = bb + (rm * GRID_W + c) * DIN + srcoff + q8;
        const float* p1 = bb + (rp * GRID_W + c) * DIN + srcoff + q8;
        const float* p2 = bb + (r * GRID_W + cm) * DIN + srcoff + q8;
        const float* p3 = bb + (r * GRID_W + cp) * DIN + srcoff + q8;
        float4 a0 = ld_sys4(p0), a1 = ld_sys4(p0 + 4);
        float4 b0 = ld_sys4(p1), b1v = ld_sys4(p1 + 4);
        float4 c0 = ld_sys4(p2), c1 = ld_sys4(p2 + 4);
        float4 d0 = ld_sys4(p3), d1 = ld_sys4(p3 + 4);
        float4 m0, m1;
        m0.x = 0.25f * (a0.x + b0.x + c0.x + d0.x);
        m0.y = 0.25f * (a0.y + b0.y + c0.y + d0.y);
        m0.z = 0.25f * (a0.z + b0.z + c0.z + d0.z);
        m0.w = 0.25f * (a0.w + b0.w + c0.w + d0.w);
        m1.x = 0.25f * (a1.x + b1v.x + c1.x + d1.x);
        m1.y = 0.25f * (a1.y + b1v.y + c1.y + d1.y);
        m1.z = 0.25f * (a1.z + b1v.z + c1.z + d1.z);
        m1.w = 0.25f * (a1.w + b1v.w + c1.w + d1.w);
        af1 = pack8(m0, m1);
    }
    if (quad < 2) {                        // xi immutable: normal cached loads
        const float* px = selfp + 2 * DD + q8;
        af2 = pack8(*(const float4*)px, *(const float4*)(px + 4));
    } else {
        af2 = (short8)(short)0;
    }

    // ---- GEMM1: H = tanh(A @ W1 + b1); B-fragments cached (hot in L1/L2) ----
    const short8* F1 = (const short8*)(ws + (phase ? OFF_F1P : OFF_F1Q));
    const short8* F2 = (const short8*)(ws + (phase ? OFF_F2P : OFF_F2Q));

    f32x4 acc1[8];
    #pragma unroll
    for (int nt = 0; nt < 8; ++nt) acc1[nt] = (f32x4){0.f, 0.f, 0.f, 0.f};
    #pragma unroll
    for (int nt = 0; nt < 8; ++nt)
        acc1[nt] = __builtin_amdgcn_mfma_f32_16x16x32_bf16(af0, F1[(0 * 8 + nt) * 64 + lane], acc1[nt], 0, 0, 0);
    #pragma unroll
    for (int nt = 0; nt < 8; ++nt)
        acc1[nt] = __builtin_amdgcn_mfma_f32_16x16x32_bf16(af1, F1[(1 * 8 + nt) * 64 + lane], acc1[nt], 0, 0, 0);
    #pragma unroll
    for (int nt = 0; nt < 8; ++nt)
        acc1[nt] = __builtin_amdgcn_mfma_f32_16x16x32_bf16(af2, F1[(2 * 8 + nt) * 64 + lane], acc1[nt], 0, 0, 0);

    // tanh -> sH (C-layout: col=lane&15, row=quad*4+reg). Wave-local rows.
    #pragma unroll
    for (int nt = 0; nt < 8; ++nt) {
        const int col = nt * 16 + l16;
        const float bias = B1[col];
        #pragma unroll
        for (int rg = 0; rg < 4; ++rg) {
            const int rowm = wv * 16 + quad * 4 + rg;
            float s = acc1[nt][rg] + bias;
            float e = __expf(2.0f * s);
            float hh = 1.0f - __fdividef(2.0f, e + 1.0f);
            sH[rowm * SH_STRIDE + col] = f2bf(hh);
        }
    }

    // ---- GEMM2: O = H @ W2 + b2 ----
    f32x4 acc2[2];
    acc2[0] = (f32x4){0.f, 0.f, 0.f, 0.f};
    acc2[1] = (f32x4){0.f, 0.f, 0.f, 0.f};
    #pragma unroll
    for (int ks = 0; ks < 4; ++ks) {
        short8 af = *(const short8*)&sH[(wv * 16 + l16) * SH_STRIDE + ks * 32 + q8];
        #pragma unroll
        for (int nt = 0; nt < 2; ++nt)
            acc2[nt] = __builtin_amdgcn_mfma_f32_16x16x32_bf16(af, F2[(ks * 2 + nt) * 64 + lane], acc2[nt], 0, 0, 0);
    }

    // ---- O -> wave-private sO, then coalesced system-scope RMW epilogue ----
    float* sOw = sO + wv * 512;            // 16 rows x 32 f32
    #pragma unroll
    for (int nt = 0; nt < 2; ++nt) {
        const int col = nt * 16 + l16;
        const float b2v = B2[col];
        #pragma unroll
        for (int rg = 0; rg < 4; ++rg)
            sOw[(quad * 4 + rg) * DD + col] = acc2[nt][rg] + b2v;
    }
    #pragma unroll
    for (int it = 0; it < 2; ++it) {
        const int slot = lane + it * 64;   // 128 float4 slots = 16 rows x 8
        const int lr = slot >> 3, seg = (slot & 7) * 4;
        float* pd = bb + (r * GRID_W + wv * 16 + lr) * DIN + dstoff + seg;
        const float* po = &sOw[lr * DD + seg];
        float4 o = ld_sys4(pd);
        o.x += dt * po[0]; o.y += dt * po[1];
        o.z += dt * po[2]; o.w += dt * po[3];
        st_sys4(pd, o);
    }
}

// Wavefront-pipelined solver: per-block step counters, neighbor-only sync.
// Lag-1 ring sync covers both flow and anti dependencies (q/p phase alternation).
__global__ __launch_bounds__(256, 2) void sympl_coop(
    float* __restrict__ state, const float* __restrict__ tfinal,
    char* __restrict__ ws,
    const float* __restrict__ b1q, const float* __restrict__ b2q,
    const float* __restrict__ b1p, const float* __restrict__ b2p)
{
    __shared__ __align__(16) ushort sH[64 * SH_STRIDE];
    __shared__ __align__(16) float  sO[4 * 512];
    uint* flags = (uint*)ws;               // one 64B line (16 uints) per block
    const int blk = blockIdx.x, tid = threadIdx.x;
    const int batch = blk >> 6, j = blk & 63;
    uint* flL = flags + (batch * 64 + ((j + 63) & 63)) * 16;
    uint* flR = flags + (batch * 64 + ((j + 1) & 63)) * 16;
    uint* flO = flags + blk * 16;

    // grid-uniform early-exit bound (immutable input -> identical on all blocks)
    float tfmax = 0.0f;
    #pragma unroll
    for (int i = 0; i < BATCH; ++i) tfmax = fmaxf(tfmax, tfinal[i]);

    float tq = 0.0f, tp = 0.0f;
    #pragma unroll 1
    for (int h = 0; h < NSTEP; ++h) {
        const int phase = h & 1;
        const float dtmax = phase ? 0.25f : ((h == 0) ? 0.125f : 0.25f);
        const float tcur  = phase ? tp : tq;
        if (tcur >= tfmax) break;          // monotone & uniform: ring stays deadlock-free
        if (h > 0 && tid == 0) {           // wait: neighbors completed step h-1
            while (__hip_atomic_load(flL, __ATOMIC_RELAXED, __HIP_MEMORY_SCOPE_SYSTEM) < (uint)h)
                __builtin_amdgcn_s_sleep(1);
            while (__hip_atomic_load(flR, __ATOMIC_RELAXED, __HIP_MEMORY_SCOPE_SYSTEM) < (uint)h)
                __builtin_amdgcn_s_sleep(1);
        }
        __syncthreads();                   // broadcast go-signal to all waves
        do_step(state, tfinal, ws,
                phase ? b1p : b1q, phase ? b2p : b2q,
                sH, sO, blk, tid, phase, tcur, dtmax);
        __syncthreads();                   // drain all waves' state stores (vmcnt 0)
        if (tid == 0)
            __hip_atomic_store(flO, (uint)(h + 1), __ATOMIC_RELAXED, __HIP_MEMORY_SCOPE_SYSTEM);
        if (phase) tp += dtmax; else tq += dtmax;
    }
}

__global__ __launch_bounds__(256, 2) void sympl_step(
    float* __restrict__ state, const float* __restrict__ tfinal,
    const char* __restrict__ ws,
    const float* __restrict__ B1, const float* __restrict__ B2,
    int phase, float tcur, float dtmax)
{
    __shared__ __align__(16) ushort sH[64 * SH_STRIDE];
    __shared__ __align__(16) float  sO[4 * 512];
    do_step(state, tfinal, ws, B1, B2, sH, sO,
            blockIdx.x, threadIdx.x, phase, tcur, dtmax);
}

extern "C" void kernel_launch(void* const* d_in, const int* in_sizes, int n_in,
                              void* d_out, int out_size, void* d_ws, size_t ws_size,
                              hipStream_t stream)
{
    const float* x   = (const float*)d_in[0];
    const float* tf  = (const float*)d_in[1];
    const float* W1q = (const float*)d_in[2];
    const float* b1q = (const float*)d_in[3];
    const float* W2q = (const float*)d_in[4];
    const float* b2q = (const float*)d_in[5];
    const float* W1p = (const float*)d_in[6];
    const float* b1p = (const float*)d_in[7];
    const float* W2p = (const float*)d_in[8];
    const float* b2p = (const float*)d_in[9];
    float* out = (float*)d_out;
    char* ws = (char*)d_ws;

    // state lives in d_out: [b][i][q(32) p(32) xi(16)]
    hipMemcpyAsync(out, x, (size_t)BATCH * NPTS * DIN * sizeof(float),
                   hipMemcpyDeviceToDevice, stream);
    hipMemsetAsync(ws, 0, NBLK * 64, stream);          // per-block step flags
    pack_weights<<<dim3(2), dim3(256), 0, stream>>>(W1q, W2q, W1p, W2p, ws);

    void* args[] = { (void*)&out, (void*)&tf, (void*)&ws,
                     (void*)&b1q, (void*)&b2q, (void*)&b1p, (void*)&b2p };
    hipError_t e = hipLaunchCooperativeKernel((const void*)sympl_coop,
                                              dim3(NBLK), dim3(256), args, 0, stream);
    if (e != hipSuccess) {
        // Fallback: same math as 34 regular launches (kernel-boundary coherence).
        float tq = 0.0f, tp = 0.0f;
        for (int h = 0; h < NSTEP; ++h) {
            const int phase = h & 1;
            const float dtmax = phase ? 0.25f : ((h == 0) ? 0.125f : 0.25f);
            const float tcur  = phase ? tp : tq;
            sympl_step<<<dim3(NBLK), dim3(256), 0, stream>>>(
                out, tf, ws, phase ? b1p : b1q, phase ? b2p : b2q,
                phase, tcur, dtmax);
            if (phase) tp += dtmax; else tq += dtmax;
        }
    }
}

// Round 8
// 291.987 us; speedup vs baseline: 12.6609x; 1.1115x over previous
//
#include <hip/hip_runtime.h>
#include <hip/hip_bf16.h>

#define GRID_W 64
#define NPTS   4096
#define BATCH  8
#define DD     32
#define DIN    80
#define HID    128
#define SH_STRIDE 136              // ushort stride (17*16B) -> conflict-free b128
#define SQ_STRIDE 36               // f32 stride for LDS state rows (144B, 16B-aligned)
#define NBLK   512                 // one grid-row per block
#define NSTEP  34                  // steps 34,35 are dead for any tf <= 4.0
// ws layout: per-block step flags (64B line each) | fragment-packed bf16 weights
#define OFF_F1Q 32768
#define OFF_F2Q (OFF_F1Q + 24*64*16)   // 24 GEMM1 frags * 64 lanes * 16B
#define OFF_F1P (OFF_F2Q + 8*64*16)    //  8 GEMM2 frags
#define OFF_F2P (OFF_F1P + 24*64*16)

typedef __attribute__((ext_vector_type(8))) short short8;
typedef __attribute__((ext_vector_type(4))) float f32x4;
typedef unsigned long long u64;

__device__ __forceinline__ ushort f2bf(float v) {
    __hip_bfloat16 h = __float2bfloat16(v);
    return __builtin_bit_cast(ushort, h);
}
__device__ __forceinline__ uint packbf(float a, float b) {
    return (uint)f2bf(a) | ((uint)f2bf(b) << 16);
}
__device__ __forceinline__ short8 pack8(float4 a, float4 b) {
    union { uint u[4]; short8 s; } t;
    t.u[0] = packbf(a.x, a.y); t.u[1] = packbf(a.z, a.w);
    t.u[2] = packbf(b.x, b.y); t.u[3] = packbf(b.z, b.w);
    return t.s;
}

// System-scope 16B load/store as 2x8B relaxed atomics (sc0 sc1: L3-coherent,
// bypass per-XCD L2). Validated rounds 5-7.
__device__ __forceinline__ float4 ld_sys4(const float* p) {
    u64 a = __hip_atomic_load((const u64*)p,       __ATOMIC_RELAXED, __HIP_MEMORY_SCOPE_SYSTEM);
    u64 b = __hip_atomic_load((const u64*)(p + 2), __ATOMIC_RELAXED, __HIP_MEMORY_SCOPE_SYSTEM);
    float4 r;
    r.x = __uint_as_float((uint)a); r.y = __uint_as_float((uint)(a >> 32));
    r.z = __uint_as_float((uint)b); r.w = __uint_as_float((uint)(b >> 32));
    return r;
}
__device__ __forceinline__ void st_sys4(float* p, float4 v) {
    u64 a = ((u64)__float_as_uint(v.y) << 32) | __float_as_uint(v.x);
    u64 b = ((u64)__float_as_uint(v.w) << 32) | __float_as_uint(v.z);
    __hip_atomic_store((u64*)p,       a, __ATOMIC_RELAXED, __HIP_MEMORY_SCOPE_SYSTEM);
    __hip_atomic_store((u64*)(p + 2), b, __ATOMIC_RELAXED, __HIP_MEMORY_SCOPE_SYSTEM);
}

// Pack W1/W2 (both sets) into MFMA B-fragment order in ws.
__global__ void pack_weights(const float* __restrict__ W1q, const float* __restrict__ W2q,
                             const float* __restrict__ W1p, const float* __restrict__ W2p,
                             char* __restrict__ ws)
{
    const int s = blockIdx.x;
    const float* W1 = s ? W1p : W1q;
    const float* W2 = s ? W2p : W2q;
    ushort* f1 = (ushort*)(ws + (s ? OFF_F1P : OFF_F1Q));
    ushort* f2 = (ushort*)(ws + (s ? OFF_F2P : OFF_F2Q));
    for (int idx = threadIdx.x; idx < 24 * 512; idx += 256) {
        int f = idx >> 9, rem = idx & 511, lane = rem >> 3, j = rem & 7;
        int ks = f >> 3, nt = f & 7;
        int k = ks * 32 + (lane >> 4) * 8 + j, n = nt * 16 + (lane & 15);
        f1[idx] = f2bf(k < DIN ? W1[k * HID + n] : 0.0f);
    }
    for (int idx = threadIdx.x; idx < 8 * 512; idx += 256) {
        int f = idx >> 9, rem = idx & 511, lane = rem >> 3, j = rem & 7;
        int ks = f >> 1, nt = f & 1;
        int k = ks * 32 + (lane >> 4) * 8 + j, n = nt * 16 + (lane & 15);
        f2[idx] = f2bf(W2[k * DD + n]);
    }
}

// LDS-resident-state wavefront solver: block r owns grid row r's q/p in LDS
// for all steps; only row-neighbor slices are read from L3 per step.
__global__ __launch_bounds__(256, 2) void sympl_coop(
    float* __restrict__ state, const float* __restrict__ tfinal,
    char* __restrict__ ws,
    const float* __restrict__ b1q, const float* __restrict__ b2q,
    const float* __restrict__ b1p, const float* __restrict__ b2p)
{
    __shared__ __align__(16) float  sQ[64 * SQ_STRIDE];
    __shared__ __align__(16) float  sP[64 * SQ_STRIDE];
    __shared__ __align__(16) ushort sH[64 * SH_STRIDE];
    __shared__ __align__(16) float  sO[4 * 512];

    uint* flags = (uint*)ws;               // one 64B line (16 uints) per block
    const int blk = blockIdx.x, tid = threadIdx.x;
    const int b = blk >> 6, r = blk & 63;
    const int wv = tid >> 6, lane = tid & 63;
    const int l16 = lane & 15, quad = lane >> 4, q8 = quad * 8;
    const int c = wv * 16 + l16;           // point column = GEMM row
    const int rm = (r + 63) & 63, rp = (r + 1) & 63;
    const int cm = (c + 63) & 63, cp = (c + 1) & 63;
    float* bb = state + (size_t)b * NPTS * DIN;

    uint* flL = flags + (b * 64 + rm) * 16;
    uint* flR = flags + (b * 64 + rp) * 16;
    uint* flO = flags + blk * 16;
    uint* myflag = (tid == 0) ? flL : flR; // lanes 0 & 1 poll both in parallel

    // ---- init: own-row q/p -> LDS; xi + W2 fragments -> registers ----
    {
        const int pt = tid >> 2, sg = (tid & 3) * 8;
        const float* src = bb + (r * GRID_W + pt) * DIN;
        float4 q0 = *(const float4*)(src + sg);
        float4 q1 = *(const float4*)(src + sg + 4);
        float4 p0 = *(const float4*)(src + DD + sg);
        float4 p1 = *(const float4*)(src + DD + sg + 4);
        *(float4*)&sQ[pt * SQ_STRIDE + sg]     = q0;
        *(float4*)&sQ[pt * SQ_STRIDE + sg + 4] = q1;
        *(float4*)&sP[pt * SQ_STRIDE + sg]     = p0;
        *(float4*)&sP[pt * SQ_STRIDE + sg + 4] = p1;
    }
    short8 af2;
    if (quad < 2) {
        const float* px = bb + (r * GRID_W + c) * DIN + 2 * DD + q8;
        af2 = pack8(*(const float4*)px, *(const float4*)(px + 4));
    } else {
        af2 = (short8)(short)0;
    }
    short8 w2q[8], w2p[8];
    {
        const short8* F2q = (const short8*)(ws + OFF_F2Q);
        const short8* F2p = (const short8*)(ws + OFF_F2P);
        #pragma unroll
        for (int i = 0; i < 8; ++i) { w2q[i] = F2q[i * 64 + lane]; w2p[i] = F2p[i * 64 + lane]; }
    }
    const float tf = tfinal[b];
    float tfmax = 0.0f;
    #pragma unroll
    for (int i = 0; i < BATCH; ++i) tfmax = fmaxf(tfmax, tfinal[i]);
    __syncthreads();                       // LDS state visible to all waves

    float tq = 0.0f, tp = 0.0f;
    #pragma unroll 1
    for (int h = 0; h < NSTEP; ++h) {
        const int phase = h & 1;           // 0: q += dt*F(p); 1: p += dt*F(q)
        const float dtmax = phase ? 0.25f : ((h == 0) ? 0.125f : 0.25f);
        const float tcur  = phase ? tp : tq;
        if (tcur >= tfmax) break;          // monotone & uniform: ring stays live
        if (h > 0 && tid < 2) {            // both neighbor flags polled in parallel
            while (__hip_atomic_load(myflag, __ATOMIC_RELAXED, __HIP_MEMORY_SCOPE_SYSTEM) < (uint)h)
                __builtin_amdgcn_s_sleep(1);
        }
        __syncthreads();

        const float dt = fminf(fmaxf(tf - tcur, 0.0f), dtmax);
        if (dt > 0.0f) {                   // block-uniform
            const int srcoff = phase ? 0 : DD;
            const int dstoff = phase ? DD : 0;
            const float* srcL = phase ? sQ : sP;
            float*       dstL = phase ? sP : sQ;

            // ---- row-neighbor slices from L3 (issue first: longest latency) ----
            const float* pu = bb + (rm * GRID_W + c) * DIN + srcoff + q8;
            const float* pw = bb + (rp * GRID_W + c) * DIN + srcoff + q8;
            float4 u0 = ld_sys4(pu), u1 = ld_sys4(pu + 4);
            float4 d0 = ld_sys4(pw), d1 = ld_sys4(pw + 4);

            // ---- self + column neighbors from LDS ----
            const float* s0 = srcL + c  * SQ_STRIDE + q8;
            const float* sm = srcL + cm * SQ_STRIDE + q8;
            const float* sp = srcL + cp * SQ_STRIDE + q8;
            float4 a0 = *(const float4*)s0, a1 = *(const float4*)(s0 + 4);
            float4 c0 = *(const float4*)sm, c1 = *(const float4*)(sm + 4);
            float4 e0 = *(const float4*)sp, e1 = *(const float4*)(sp + 4);
            float4 m0, m1;
            m0.x = 0.25f * (u0.x + d0.x + c0.x + e0.x);
            m0.y = 0.25f * (u0.y + d0.y + c0.y + e0.y);
            m0.z = 0.25f * (u0.z + d0.z + c0.z + e0.z);
            m0.w = 0.25f * (u0.w + d0.w + c0.w + e0.w);
            m1.x = 0.25f * (u1.x + d1.x + c1.x + e1.x);
            m1.y = 0.25f * (u1.y + d1.y + c1.y + e1.y);
            m1.z = 0.25f * (u1.z + d1.z + c1.z + e1.z);
            m1.w = 0.25f * (u1.w + d1.w + c1.w + e1.w);
            short8 af0 = pack8(a0, a1);
            short8 af1 = pack8(m0, m1);

            // ---- GEMM1: H = tanh(A @ W1 + b1); F1 streams from L1/L2 ----
            const short8* F1 = (const short8*)(ws + (phase ? OFF_F1P : OFF_F1Q));
            const float*  B1 = phase ? b1p : b1q;
            const float*  B2 = phase ? b2p : b2q;

            f32x4 acc1[8];
            #pragma unroll
            for (int nt = 0; nt < 8; ++nt) acc1[nt] = (f32x4){0.f, 0.f, 0.f, 0.f};
            #pragma unroll
            for (int nt = 0; nt < 8; ++nt)
                acc1[nt] = __builtin_amdgcn_mfma_f32_16x16x32_bf16(af0, F1[(0 * 8 + nt) * 64 + lane], acc1[nt], 0, 0, 0);
            #pragma unroll
            for (int nt = 0; nt < 8; ++nt)
                acc1[nt] = __builtin_amdgcn_mfma_f32_16x16x32_bf16(af1, F1[(1 * 8 + nt) * 64 + lane], acc1[nt], 0, 0, 0);
            #pragma unroll
            for (int nt = 0; nt < 8; ++nt)
                acc1[nt] = __builtin_amdgcn_mfma_f32_16x16x32_bf16(af2, F1[(2 * 8 + nt) * 64 + lane], acc1[nt], 0, 0, 0);

            // tanh -> sH (C-layout: col=lane&15, row=quad*4+reg). Wave-local rows.
            #pragma unroll
            for (int nt = 0; nt < 8; ++nt) {
                const int col = nt * 16 + l16;
                const float bias = B1[col];
                #pragma unroll
                for (int rg = 0; rg < 4; ++rg) {
                    const int rowm = wv * 16 + quad * 4 + rg;
                    float s = acc1[nt][rg] + bias;
                    float e = __expf(2.0f * s);
                    float hh = 1.0f - __fdividef(2.0f, e + 1.0f);
                    sH[rowm * SH_STRIDE + col] = f2bf(hh);
                }
            }

            // ---- GEMM2: O = H @ W2 + b2 (W2 fragments register-resident) ----
            f32x4 acc2[2];
            acc2[0] = (f32x4){0.f, 0.f, 0.f, 0.f};
            acc2[1] = (f32x4){0.f, 0.f, 0.f, 0.f};
            if (phase) {
                #pragma unroll
                for (int ks = 0; ks < 4; ++ks) {
                    short8 af = *(const short8*)&sH[(wv * 16 + l16) * SH_STRIDE + ks * 32 + q8];
                    acc2[0] = __builtin_amdgcn_mfma_f32_16x16x32_bf16(af, w2p[ks * 2 + 0], acc2[0], 0, 0, 0);
                    acc2[1] = __builtin_amdgcn_mfma_f32_16x16x32_bf16(af, w2p[ks * 2 + 1], acc2[1], 0, 0, 0);
                }
            } else {
                #pragma unroll
                for (int ks = 0; ks < 4; ++ks) {
                    short8 af = *(const short8*)&sH[(wv * 16 + l16) * SH_STRIDE + ks * 32 + q8];
                    acc2[0] = __builtin_amdgcn_mfma_f32_16x16x32_bf16(af, w2q[ks * 2 + 0], acc2[0], 0, 0, 0);
                    acc2[1] = __builtin_amdgcn_mfma_f32_16x16x32_bf16(af, w2q[ks * 2 + 1], acc2[1], 0, 0, 0);
                }
            }

            // ---- O -> wave-private sO, then LDS-state update + sys publish ----
            float* sOw = sO + wv * 512;        // 16 rows x 32 f32
            #pragma unroll
            for (int nt = 0; nt < 2; ++nt) {
                const int col = nt * 16 + l16;
                const float b2v = B2[col];
                #pragma unroll
                for (int rg = 0; rg < 4; ++rg)
                    sOw[(quad * 4 + rg) * DD + col] = acc2[nt][rg] + b2v;
            }
            #pragma unroll
            for (int it = 0; it < 2; ++it) {
                const int slot = lane + it * 64;   // 128 float4 slots = 16 rows x 8
                const int lr = slot >> 3, seg = (slot & 7) * 4;
                const int pt = wv * 16 + lr;       // wave-private rows: no race
                const float* po = &sOw[lr * DD + seg];
                float* pl = dstL + pt * SQ_STRIDE + seg;
                float4 o = *(const float4*)pl;
                o.x += dt * po[0]; o.y += dt * po[1];
                o.z += dt * po[2]; o.w += dt * po[3];
                *(float4*)pl = o;
                st_sys4(bb + (r * GRID_W + pt) * DIN + dstoff + seg, o);
            }
        }
        __syncthreads();                   // drain all waves' stores (vmcnt 0)
        if (tid == 0)
            __hip_atomic_store(flO, (uint)(h + 1), __ATOMIC_RELAXED, __HIP_MEMORY_SCOPE_SYSTEM);
        if (phase) tp += dtmax; else tq += dtmax;
    }
}

// ---------------- fallback path (round-7-proven, global state) ----------------
__global__ __launch_bounds__(256, 2) void sympl_step(
    float* __restrict__ state, const float* __restrict__ tfinal,
    const char* __restrict__ ws,
    const float* __restrict__ B1, const float* __restrict__ B2,
    int phase, float tcur, float dtmax)
{
    __shared__ __align__(16) ushort sH[64 * SH_STRIDE];
    __shared__ __align__(16) float  sO[4 * 512];
    const int blk = blockIdx.x, tid = threadIdx.x;
    const int wv = tid >> 6, lane = tid & 63;
    const int l16 = lane & 15, quad = lane >> 4, q8 = quad * 8;
    const int b = blk >> 6, r = blk & 63;
    const int c = wv * 16 + l16;

    const float tf = tfinal[b];
    const float dt = fminf(fmaxf(tf - tcur, 0.0f), dtmax);
    if (dt <= 0.0f) return;

    const int srcoff = phase ? 0 : DD;
    const int dstoff = phase ? DD : 0;
    float* bb = state + (size_t)b * NPTS * DIN;
    const float* selfp = bb + (r * GRID_W + c) * DIN;
    const int rm = (r + 63) & 63, rp = (r + 1) & 63;
    const int cm = (c + 63) & 63, cp = (c + 1) & 63;
    short8 af0, af1, af2;
    {
        const float* ps = selfp + srcoff + q8;
        af0 = pack8(*(const float4*)ps, *(const float4*)(ps + 4));
    }
    {
        const float* p0 = bb + (rm * GRID_W + c) * DIN + srcoff + q8;
        const float* p1 = bb + (rp * GRID_W + c) * DIN + srcoff + q8;
        const float* p2 = bb + (r * GRID_W + cm) * DIN + srcoff + q8;
        const float* p3 = bb + (r * GRID_W + cp) * DIN + srcoff + q8;
        float4 a0 = *(const float4*)p0, a1 = *(const float4*)(p0 + 4);
        float4 b0 = *(const float4*)p1, b1v = *(const float4*)(p1 + 4);
        float4 c0 = *(const float4*)p2, c1 = *(const float4*)(p2 + 4);
        float4 d0 = *(const float4*)p3, d1 = *(const float4*)(p3 + 4);
        float4 m0, m1;
        m0.x = 0.25f * (a0.x + b0.x + c0.x + d0.x);
        m0.y = 0.25f * (a0.y + b0.y + c0.y + d0.y);
        m0.z = 0.25f * (a0.z + b0.z + c0.z + d0.z);
        m0.w = 0.25f * (a0.w + b0.w + c0.w + d0.w);
        m1.x = 0.25f * (a1.x + b1v.x + c1.x + d1.x);
        m1.y = 0.25f * (a1.y + b1v.y + c1.y + d1.y);
        m1.z = 0.25f * (a1.z + b1v.z + c1.z + d1.z);
        m1.w = 0.25f * (a1.w + b1v.w + c1.w + d1.w);
        af1 = pack8(m0, m1);
    }
    if (quad < 2) {
        const float* px = selfp + 2 * DD + q8;
        af2 = pack8(*(const float4*)px, *(const float4*)(px + 4));
    } else {
        af2 = (short8)(short)0;
    }
    const short8* F1 = (const short8*)(ws + (phase ? OFF_F1P : OFF_F1Q));
    const short8* F2 = (const short8*)(ws + (phase ? OFF_F2P : OFF_F2Q));
    f32x4 acc1[8];
    #pragma unroll
    for (int nt = 0; nt < 8; ++nt) acc1[nt] = (f32x4){0.f, 0.f, 0.f, 0.f};
    #pragma unroll
    for (int nt = 0; nt < 8; ++nt)
        acc1[nt] = __builtin_amdgcn_mfma_f32_16x16x32_bf16(af0, F1[(0 * 8 + nt) * 64 + lane], acc1[nt], 0, 0, 0);
    #pragma unroll
    for (int nt = 0; nt < 8; ++nt)
        acc1[nt] = __builtin_amdgcn_mfma_f32_16x16x32_bf16(af1, F1[(1 * 8 + nt) * 64 + lane], acc1[nt], 0, 0, 0);
    #pragma unroll
    for (int nt = 0; nt < 8; ++nt)
        acc1[nt] = __builtin_amdgcn_mfma_f32_16x16x32_bf16(af2, F1[(2 * 8 + nt) * 64 + lane], acc1[nt], 0, 0, 0);
    #pragma unroll
    for (int nt = 0; nt < 8; ++nt) {
        const int col = nt * 16 + l16;
        const float bias = B1[col];
        #pragma unroll
        for (int rg = 0; rg < 4; ++rg) {
            const int rowm = wv * 16 + quad * 4 + rg;
            float s = acc1[nt][rg] + bias;
            float e = __expf(2.0f * s);
            float hh = 1.0f - __fdividef(2.0f, e + 1.0f);
            sH[rowm * SH_STRIDE + col] = f2bf(hh);
        }
    }
    f32x4 acc2[2];
    acc2[0] = (f32x4){0.f, 0.f, 0.f, 0.f};
    acc2[1] = (f32x4){0.f, 0.f, 0.f, 0.f};
    #pragma unroll
    for (int ks = 0; ks < 4; ++ks) {
        short8 af = *(const short8*)&sH[(wv * 16 + l16) * SH_STRIDE + ks * 32 + q8];
        #pragma unroll
        for (int nt = 0; nt < 2; ++nt)
            acc2[nt] = __builtin_amdgcn_mfma_f32_16x16x32_bf16(af, F2[(ks * 2 + nt) * 64 + lane], acc2[nt], 0, 0, 0);
    }
    float* sOw = sO + wv * 512;
    #pragma unroll
    for (int nt = 0; nt < 2; ++nt) {
        const int col = nt * 16 + l16;
        const float b2v = B2[col];
        #pragma unroll
        for (int rg = 0; rg < 4; ++rg)
            sOw[(quad * 4 + rg) * DD + col] = acc2[nt][rg] + b2v;
    }
    #pragma unroll
    for (int it = 0; it < 2; ++it) {
        const int slot = lane + it * 64;
        const int lr = slot >> 3, seg = (slot & 7) * 4;
        float* pd = bb + (r * GRID_W + wv * 16 + lr) * DIN + dstoff + seg;
        const float* po = &sOw[lr * DD + seg];
        float4 o = *(const float4*)pd;
        o.x += dt * po[0]; o.y += dt * po[1];
        o.z += dt * po[2]; o.w += dt * po[3];
        *(float4*)pd = o;
    }
}

extern "C" void kernel_launch(void* const* d_in, const int* in_sizes, int n_in,
                              void* d_out, int out_size, void* d_ws, size_t ws_size,
                              hipStream_t stream)
{
    const float* x   = (const float*)d_in[0];
    const float* tf  = (const float*)d_in[1];
    const float* W1q = (const float*)d_in[2];
    const float* b1q = (const float*)d_in[3];
    const float* W2q = (const float*)d_in[4];
    const float* b2q = (const float*)d_in[5];
    const float* W1p = (const float*)d_in[6];
    const float* b1p = (const float*)d_in[7];
    const float* W2p = (const float*)d_in[8];
    const float* b2p = (const float*)d_in[9];
    float* out = (float*)d_out;
    char* ws = (char*)d_ws;

    // state lives in d_out: [b][i][q(32) p(32) xi(16)]
    hipMemcpyAsync(out, x, (size_t)BATCH * NPTS * DIN * sizeof(float),
                   hipMemcpyDeviceToDevice, stream);
    hipMemsetAsync(ws, 0, NBLK * 64, stream);          // per-block step flags
    pack_weights<<<dim3(2), dim3(256), 0, stream>>>(W1q, W2q, W1p, W2p, ws);

    void* args[] = { (void*)&out, (void*)&tf, (void*)&ws,
                     (void*)&b1q, (void*)&b2q, (void*)&b1p, (void*)&b2p };
    hipError_t e = hipLaunchCooperativeKernel((const void*)sympl_coop,
                                              dim3(NBLK), dim3(256), args, 0, stream);
    if (e != hipSuccess) {
        // Fallback: same math as 34 regular launches (kernel-boundary coherence).
        float tq = 0.0f, tp = 0.0f;
        for (int h = 0; h < NSTEP; ++h) {
            const int phase = h & 1;
            const float dtmax = phase ? 0.25f : ((h == 0) ? 0.125f : 0.25f);
            const float tcur  = phase ? tp : tq;
            sympl_step<<<dim3(NBLK), dim3(256), 0, stream>>>(
                out, tf, ws, phase ? b1p : b1q, phase ? b2p : b2q,
                phase, tcur, dtmax);
            if (phase) tp += dtmax; else tq += dtmax;
        }
    }
}